// Round 4
// baseline (412.799 us; speedup 1.0000x reference)
//
#include <hip/hip_runtime.h>
#include <hip/hip_bf16.h>
#include <stdint.h>

// ---- problem constants ----
#define C_DIM 1024
#define H_DIM 16
#define K_DIM 64
#define T_CH 128
#define TT_DIM 4096
#define B_DIM 4
#define N_CH 32
#define M_ROWS 16384  // B*TT

typedef __attribute__((ext_vector_type(8))) __bf16 bf16x8;
typedef __attribute__((ext_vector_type(4))) float floatx4;

__device__ __forceinline__ float bf2f(ushort u) {
  union { uint32_t i; float f; } v; v.i = ((uint32_t)u) << 16; return v.f;
}
__device__ __forceinline__ ushort f2bf(float f) {
  union { float f; uint32_t i; } v; v.f = f;
  return (ushort)((v.i + 0x7fffu + ((v.i >> 16) & 1u)) >> 16);  // RNE
}

#define GLOAD_LDS16(g, l)                                                     \
  __builtin_amdgcn_global_load_lds(                                           \
      (const __attribute__((address_space(1))) void*)(g),                     \
      (__attribute__((address_space(3))) void*)(l), 16, 0, 0)

// ============================================================
// 1) time-shift mix: xr/xk/xv/xg (bf16) from x (fp32)
//    v3: 8 elems/thread, 16B stores (was 8B) for full store width.
// ============================================================
__global__ __launch_bounds__(256) void mix_kernel(
    const float* __restrict__ x,
    const float* __restrict__ mk, const float* __restrict__ mv,
    const float* __restrict__ mr, const float* __restrict__ mg,
    ushort* __restrict__ xr, ushort* __restrict__ xk,
    ushort* __restrict__ xv, ushort* __restrict__ xg) {
  long idx = (long)blockIdx.x * 256 + threadIdx.x;
  long e = idx * 8;
  int c = (int)(e & (C_DIM - 1));
  long row = e >> 10;
  int t = (int)(row & (TT_DIM - 1));
  floatx4 xc0 = *(const floatx4*)(x + e);
  floatx4 xc1 = *(const floatx4*)(x + e + 4);
  floatx4 xp0 = {0.f, 0.f, 0.f, 0.f};
  floatx4 xp1 = {0.f, 0.f, 0.f, 0.f};
  if (t != 0) {
    xp0 = *(const floatx4*)(x + e - C_DIM);
    xp1 = *(const floatx4*)(x + e - C_DIM + 4);
  }
  floatx4 d0 = xc0 - xp0;
  floatx4 d1 = xc1 - xp1;
  union { ushort u[8]; uint4 q; } pk;
#define ST(dst, mptr)                                                         \
  {                                                                           \
    floatx4 m0 = *(const floatx4*)((mptr) + c);                               \
    floatx4 m1 = *(const floatx4*)((mptr) + c + 4);                           \
    floatx4 o0 = xp0 + d0 * m0;                                               \
    floatx4 o1 = xp1 + d1 * m1;                                               \
    pk.u[0] = f2bf(o0.x); pk.u[1] = f2bf(o0.y);                               \
    pk.u[2] = f2bf(o0.z); pk.u[3] = f2bf(o0.w);                               \
    pk.u[4] = f2bf(o1.x); pk.u[5] = f2bf(o1.y);                               \
    pk.u[6] = f2bf(o1.z); pk.u[7] = f2bf(o1.w);                               \
    *(uint4*)((dst) + e) = pk.q;                                              \
  }
  ST(xk, mk) ST(xv, mv) ST(xr, mr) ST(xg, mg)
#undef ST
}

// ============================================================
// 2) fp32 -> bf16 weight conversion (5 weights concatenated)
//    v2: 8 elems/thread, 16B stores.
// ============================================================
__global__ __launch_bounds__(256) void wconv_kernel(
    const float* __restrict__ w0, const float* __restrict__ w1,
    const float* __restrict__ w2, const float* __restrict__ w3,
    const float* __restrict__ w4, ushort* __restrict__ o) {
  long idx = (long)blockIdx.x * 256 + threadIdx.x;
  long e = idx * 8;
  int wi = (int)(e >> 20);
  long off = e & ((1L << 20) - 1);
  const float* src = wi == 0 ? w0 : wi == 1 ? w1 : wi == 2 ? w2 : wi == 3 ? w3 : w4;
  floatx4 v0 = *(const floatx4*)(src + off);
  floatx4 v1 = *(const floatx4*)(src + off + 4);
  union { ushort u[8]; uint4 q; } pk;
  pk.u[0] = f2bf(v0.x); pk.u[1] = f2bf(v0.y);
  pk.u[2] = f2bf(v0.z); pk.u[3] = f2bf(v0.w);
  pk.u[4] = f2bf(v1.x); pk.u[5] = f2bf(v1.y);
  pk.u[6] = f2bf(v1.z); pk.u[7] = f2bf(v1.w);
  *(uint4*)(o + e) = pk.q;
}

// ============================================================
// 3) bf16 GEMM body: C[M,N] = A[M,K] * Bt[N,K]^T  (256x256 8-phase)
//    Shared by gemm_bt (single) and gemm_pair (two independent
//    GEMMs in one launch).  Schedule identical to round-3 kernel.
// ============================================================
#define BARX() __builtin_amdgcn_s_barrier()
#define SCHEDB() __builtin_amdgcn_sched_barrier(0)
#define VMW4() asm volatile("s_waitcnt vmcnt(4)" ::: "memory")
#define VMW0() asm volatile("s_waitcnt vmcnt(0)" ::: "memory")
#define LGKW() asm volatile("s_waitcnt lgkmcnt(0)" ::: "memory")

template <int EPI>
__device__ __forceinline__ void gemm_body(
    const ushort* __restrict__ A, const ushort* __restrict__ Bt,
    void* __restrict__ Cout, ushort* smem, int bm, int bn) {
  const int tid = threadIdx.x;
  const int lane = tid & 63, w = tid >> 6;
  const int q = lane >> 4, l16 = lane & 15;
  const int wm = w >> 2, wn = w & 3;

  const int r8 = tid >> 3;
  const int c8 = ((tid & 7) ^ (r8 & 7)) * 8;  // pre-swizzled global col
  const ushort* gA = A + (long)(bm * 256 + r8) * C_DIM + c8;
  const ushort* gB = Bt + (long)(bn * 256 + r8) * C_DIM + c8;

  const char* sB = (const char*)smem;
  const int arow = (wm * 128 + l16) * 128;
  const int brow = (wn * 64 + l16) * 128;
  const int swz = (l16 & 7) << 4;
  const int csv[2] = {(q << 4) ^ swz, ((4 + q) << 4) ^ swz};

  floatx4 acc[8][4] = {};
  bf16x8 af[4][2];
  bf16x8 bfv[4][2];

#define STAGE(ISA, sl, hh, tile)                                              \
  do {                                                                        \
    const ushort* g_ = (ISA ? gA : gB) + ((hh) * 131072 + (tile) * 64);       \
    ushort* l_ = smem + ((ISA ? 0 : 32768) + (sl) * 16384 + (hh) * 8192 +     \
                         w * 512);                                            \
    GLOAD_LDS16(g_, l_);                                                      \
    GLOAD_LDS16(g_ + 65536, l_ + 4096);                                       \
  } while (0)

#define READ_A(sl, qr)                                                        \
  do {                                                                        \
    _Pragma("unroll") for (int i_ = 0; i_ < 4; ++i_) {                        \
      af[i_][0] = *(const bf16x8*)(sB + (sl) * 32768 + arow + (qr) * 8192 +   \
                                   i_ * 2048 + csv[0]);                       \
      af[i_][1] = *(const bf16x8*)(sB + (sl) * 32768 + arow + (qr) * 8192 +   \
                                   i_ * 2048 + csv[1]);                       \
    }                                                                         \
  } while (0)

#define READ_B(sl, qc)                                                        \
  do {                                                                        \
    _Pragma("unroll") for (int j_ = 0; j_ < 2; ++j_) {                        \
      bfv[(qc) * 2 + j_][0] = *(const bf16x8*)(sB + 65536 + (sl) * 32768 +    \
                                               brow + (qc) * 4096 +           \
                                               j_ * 2048 + csv[0]);           \
      bfv[(qc) * 2 + j_][1] = *(const bf16x8*)(sB + 65536 + (sl) * 32768 +    \
                                               brow + (qc) * 4096 +           \
                                               j_ * 2048 + csv[1]);           \
    }                                                                         \
  } while (0)

#define MFMA_Q(qr, qc)                                                        \
  do {                                                                        \
    __builtin_amdgcn_s_setprio(1);                                            \
    _Pragma("unroll") for (int i_ = 0; i_ < 4; ++i_)                          \
        _Pragma("unroll") for (int j_ = 0; j_ < 2; ++j_) {                    \
      acc[(qr) * 4 + i_][(qc) * 2 + j_] =                                     \
          __builtin_amdgcn_mfma_f32_16x16x32_bf16(                            \
              af[i_][0], bfv[(qc) * 2 + j_][0],                               \
              acc[(qr) * 4 + i_][(qc) * 2 + j_], 0, 0, 0);                    \
      acc[(qr) * 4 + i_][(qc) * 2 + j_] =                                     \
          __builtin_amdgcn_mfma_f32_16x16x32_bf16(                            \
              af[i_][1], bfv[(qc) * 2 + j_][1],                               \
              acc[(qr) * 4 + i_][(qc) * 2 + j_], 0, 0, 0);                    \
    }                                                                         \
    __builtin_amdgcn_s_setprio(0);                                            \
  } while (0)

  // ---- prologue: A/B of tile0 -> slot0, B of tile1 -> slot1 ----
  STAGE(1, 0, 0, 0); STAGE(1, 0, 1, 0);
  STAGE(0, 0, 0, 0); STAGE(0, 0, 1, 0);
  STAGE(0, 1, 0, 1); STAGE(0, 1, 1, 1);
  VMW4();  // t0's 8 loads done; B-t1's 4 stay in flight
  BARX();
  SCHEDB();
  READ_B(0, 0);  // bfv[0..1] <- B(slot0, qc0)

#pragma unroll 1
  for (int i = 0; i < 7; ++i) {
    const int t1 = 2 * i + 1, tn0 = 2 * i + 2, tn1 = 2 * i + 3;
    READ_A(0, 0); STAGE(1, 1, 0, t1);
    BARX(); SCHEDB(); READ_B(0, 1); MFMA_Q(0, 0); LGKW(); BARX();
    STAGE(1, 1, 1, t1);
    BARX(); SCHEDB(); MFMA_Q(0, 1); LGKW(); BARX();
    READ_A(0, 1); STAGE(0, 0, 0, tn0);
    BARX(); SCHEDB(); MFMA_Q(1, 0); LGKW(); BARX();
    STAGE(0, 0, 1, tn0); VMW4();
    BARX(); SCHEDB(); READ_B(1, 0); MFMA_Q(1, 1); LGKW(); BARX();
    READ_A(1, 0); STAGE(1, 0, 0, tn0);
    BARX(); SCHEDB(); READ_B(1, 1); MFMA_Q(0, 0); LGKW(); BARX();
    STAGE(1, 0, 1, tn0);
    BARX(); SCHEDB(); MFMA_Q(0, 1); LGKW(); BARX();
    READ_A(1, 1); STAGE(0, 1, 0, tn1);
    BARX(); SCHEDB(); MFMA_Q(1, 0); LGKW(); BARX();
    STAGE(0, 1, 1, tn1); VMW4();
    BARX(); SCHEDB(); READ_B(0, 0); MFMA_Q(1, 1); LGKW(); BARX();
  }
  // ---- tail pair (tiles 14,15; only A-15 still needs staging) ----
  READ_A(0, 0); STAGE(1, 1, 0, 15);
  BARX(); SCHEDB(); READ_B(0, 1); MFMA_Q(0, 0); LGKW(); BARX();
  STAGE(1, 1, 1, 15);
  BARX(); SCHEDB(); MFMA_Q(0, 1); LGKW(); BARX();
  READ_A(0, 1);
  BARX(); SCHEDB(); MFMA_Q(1, 0); LGKW(); BARX();
  VMW0();  // drain: tile15 A+B fully landed
  BARX(); SCHEDB(); READ_B(1, 0); MFMA_Q(1, 1); LGKW(); BARX();
  READ_A(1, 0);
  BARX(); SCHEDB(); READ_B(1, 1); MFMA_Q(0, 0); LGKW(); BARX();
  BARX(); SCHEDB(); MFMA_Q(0, 1); LGKW(); BARX();
  READ_A(1, 1);
  BARX(); SCHEDB(); MFMA_Q(1, 0); LGKW(); BARX();
  BARX(); MFMA_Q(1, 1);

  // ---- epilogue: C write ----
  const int row0 = bm * 256 + wm * 128 + q * 4;
  const int col0 = bn * 256 + wn * 64 + l16;
#pragma unroll
  for (int fi = 0; fi < 8; ++fi)
#pragma unroll
    for (int fj = 0; fj < 4; ++fj)
#pragma unroll
      for (int rg = 0; rg < 4; ++rg) {
        long off = (long)(row0 + fi * 16 + rg) * C_DIM + col0 + fj * 16;
        float val = acc[fi][fj][rg];
        if (EPI == 1) val = val / (1.f + expf(-val));  // silu
        if (EPI == 2)
          ((float*)Cout)[off] = val;
        else
          ((ushort*)Cout)[off] = f2bf(val);
      }
#undef STAGE
#undef READ_A
#undef READ_B
#undef MFMA_Q
}

// single GEMM (grid 256, used for the final o-projection)
template <int EPI>
__global__ __launch_bounds__(512, 2) void gemm_bt(
    const ushort* __restrict__ A, const ushort* __restrict__ Bt,
    void* __restrict__ Cout) {
  __shared__ __align__(16) ushort smem[65536];  // 128 KiB
  const int id = blockIdx.x;
  const int wg = (id & 7) * 32 + (id >> 3);
  gemm_body<EPI>(A, Bt, Cout, smem, wg >> 2, wg & 3);
}

// two independent GEMMs in one launch (grid 512):
// XCDs 0-3 run GEMM0 (EPI=0), XCDs 4-7 run GEMM1 (EPI=EPI1).
template <int EPI1>
__global__ __launch_bounds__(512, 2) void gemm_pair(
    const ushort* __restrict__ A0, const ushort* __restrict__ B0,
    void* __restrict__ C0,
    const ushort* __restrict__ A1, const ushort* __restrict__ B1,
    void* __restrict__ C1) {
  __shared__ __align__(16) ushort smem[65536];  // 128 KiB
  const int id = blockIdx.x;
  const int wgg = (id & 7) * 64 + (id >> 3);
  const int inner = wgg & 255;
  const int bm = inner >> 2, bn = inner & 3;
  if (wgg < 256)
    gemm_body<0>(A0, B0, C0, smem, bm, bn);
  else
    gemm_body<EPI1>(A1, B1, C1, smem, bm, bn);
}

// ============================================================
// 4a) per-chunk state contribution: Zc = vv^T @ (kk*wk)   (bf16)
// ============================================================
__global__ __launch_bounds__(256) void chunk_state(
    const ushort* __restrict__ kB, const ushort* __restrict__ vB,
    const float* __restrict__ td, ushort* __restrict__ Zc) {
  __shared__ __align__(16) ushort vt_s[64 * 136];
  __shared__ __align__(16) ushort kwt_s[64 * 136];
  int blk = blockIdx.x;
  int bh = blk >> 5, n = blk & 31;
  int b = bh >> 4, h = bh & 15;
  int tid = threadIdx.x;
  int lane = tid & 63, w = tid >> 6;
  int q = lane >> 4, l16 = lane & 15;
  float etd = expf(td[h]);
  long cbase = ((long)b * TT_DIM + n * T_CH) * C_DIM + h * K_DIM;

#pragma unroll
  for (int it = 0; it < 4; it++) {
    int chunk = it * 256 + tid;
    int row = chunk >> 3;
    int cc = (chunk & 7) * 8;
    long ga = cbase + (long)row * C_DIM + cc;
    uint4 kv4 = *(const uint4*)(kB + ga);
    uint4 vv4 = *(const uint4*)(vB + ga);
    float wkj = expf(-(float)(T_CH - 1 - row) * etd);
    const ushort* kp = (const ushort*)&kv4;
    const ushort* vp = (const ushort*)&vv4;
    int cb2 = row >> 3;
#pragma unroll
    for (int e2 = 0; e2 < 8; e2++) {
      int vr = cc + e2;
      int ph = vr * 136 + ((cb2 ^ ((vr >> 3) & 7)) << 3) + (row & 7);
      kwt_s[ph] = f2bf(bf2f(kp[e2]) * wkj);
      vt_s[ph] = vp[e2];
    }
  }
  __syncthreads();

  floatx4 accZ[4] = {};
#pragma unroll
  for (int js = 0; js < 128; js += 32) {
    int cb = q + (js >> 3);
    int vrA = w * 16 + l16;
    bf16x8 av = *(const bf16x8*)&vt_s[vrA * 136 + ((cb ^ ((vrA >> 3) & 7)) << 3)];
    bf16x8 bk3[4];
#pragma unroll
    for (int kt = 0; kt < 4; kt++) {
      int vrB = kt * 16 + l16;
      bk3[kt] = *(const bf16x8*)&kwt_s[vrB * 136 + ((cb ^ ((vrB >> 3) & 7)) << 3)];
    }
#pragma unroll
    for (int kt = 0; kt < 4; kt++)
      accZ[kt] = __builtin_amdgcn_mfma_f32_16x16x32_bf16(av, bk3[kt], accZ[kt], 0, 0, 0);
  }
  long zbase = (long)blk * 4096;
#pragma unroll
  for (int kt = 0; kt < 4; kt++)
#pragma unroll
    for (int rg = 0; rg < 4; rg++)
      Zc[zbase + (w * 16 + q * 4 + rg) * 64 + kt * 16 + l16] = f2bf(accZ[kt][rg]);
}

// ============================================================
// 4b) state scan: Sb[bh][n] = state BEFORE chunk n
// ============================================================
__global__ __launch_bounds__(256) void state_scan(
    const ushort* __restrict__ Zc, const float* __restrict__ td,
    ushort* __restrict__ Sb) {
  long tg = (long)blockIdx.x * 256 + threadIdx.x;
  int bh = (int)(tg >> 12);
  int e = (int)(tg & 4095);
  int h = bh & 15;
  float wsf = expf(-128.f * expf(td[h]));
  float s = 0.f;
  long base = (long)bh * N_CH * 4096 + e;
#pragma unroll
  for (int n = 0; n < N_CH; n++) {
    Sb[base + n * 4096] = f2bf(s);
    s = wsf * s + bf2f(Zc[base + n * 4096]);
  }
}

// ============================================================
// 4c) per-chunk output + GroupNorm + *g -> gy (bf16)
// ============================================================
__global__ __launch_bounds__(512, 4) void chunk_out(
    const ushort* __restrict__ rB, const ushort* __restrict__ kB,
    const ushort* __restrict__ vB, const ushort* __restrict__ gBuf,
    const ushort* __restrict__ Sb,
    const float* __restrict__ td, const float* __restrict__ tf,
    const float* __restrict__ lnw, const float* __restrict__ lnb,
    ushort* __restrict__ gy) {
  __shared__ __align__(16) ushort rr_s[128 * 72];
  __shared__ __align__(16) ushort un_s[128 * 136];  // kk then P
  __shared__ __align__(16) ushort vt_s[64 * 136];   // swizzled v^T
  __shared__ __align__(16) ushort z_s[64 * 72];
  __shared__ float pw_s[128];  // decay^d table

  int blk = blockIdx.x;
  int bh = blk >> 5, n = blk & 31;
  int b = bh >> 4, h = bh & 15;
  int tid = threadIdx.x;
  int lane = tid & 63, w = tid >> 6;  // w 0..7
  int q = lane >> 4, l16 = lane & 15;

  float etd = expf(td[h]);
  float u = tf[h];
  long cbase = ((long)b * TT_DIM + n * T_CH) * C_DIM + h * K_DIM;

  if (tid < 128) pw_s[tid] = expf(-(float)tid * etd);

#pragma unroll
  for (int it = 0; it < 2; it++) {
    int chunk = it * 512 + tid;
    int row = chunk >> 3;
    int cc = (chunk & 7) * 8;
    long ga = cbase + (long)row * C_DIM + cc;
    *(uint4*)&rr_s[row * 72 + cc] = *(const uint4*)(rB + ga);
    *(uint4*)&un_s[row * 136 + cc] = *(const uint4*)(kB + ga);
    uint4 vv4 = *(const uint4*)(vB + ga);
    const ushort* vp = (const ushort*)&vv4;
    int cb2 = row >> 3;
#pragma unroll
    for (int e2 = 0; e2 < 8; e2++) {
      int vr = cc + e2;
      vt_s[vr * 136 + ((cb2 ^ ((vr >> 3) & 7)) << 3) + (row & 7)] = vp[e2];
    }
  }
  {
    long sbase = (long)blk * 4096;
    int v = tid >> 3, c0 = (tid & 7) * 8;
    *(uint4*)&z_s[v * 72 + c0] = *(const uint4*)(Sb + sbase + v * 64 + c0);
  }
  __syncthreads();

  // accA: P = r @ kk^T ; wave quadrant 32 rows x 64 cols
  int ar0 = (w >> 1) * 32, ac0 = (w & 1) * 64;
  floatx4 accA[2][4] = {};
#pragma unroll
  for (int ks = 0; ks < 64; ks += 32) {
    bf16x8 af[2], bk2[4];
#pragma unroll
    for (int i = 0; i < 2; i++)
      af[i] = *(const bf16x8*)&rr_s[(ar0 + i * 16 + l16) * 72 + q * 8 + ks];
#pragma unroll
    for (int j = 0; j < 4; j++)
      bk2[j] = *(const bf16x8*)&un_s[(ac0 + j * 16 + l16) * 136 + q * 8 + ks];
#pragma unroll
    for (int mi = 0; mi < 2; mi++)
#pragma unroll
      for (int nj = 0; nj < 4; nj++)
        accA[mi][nj] = __builtin_amdgcn_mfma_f32_16x16x32_bf16(
            af[mi], bk2[nj], accA[mi][nj], 0, 0, 0);
  }

  // accB: r @ S^T ; wave rows 16
  int i0 = w * 16;
  floatx4 accB[4] = {};
#pragma unroll
  for (int ks = 0; ks < 64; ks += 32) {
    bf16x8 af2 = *(const bf16x8*)&rr_s[(i0 + l16) * 72 + q * 8 + ks];
    bf16x8 bz[4];
#pragma unroll
    for (int vt2 = 0; vt2 < 4; vt2++)
      bz[vt2] = *(const bf16x8*)&z_s[(vt2 * 16 + l16) * 72 + q * 8 + ks];
#pragma unroll
    for (int vt2 = 0; vt2 < 4; vt2++)
      accB[vt2] = __builtin_amdgcn_mfma_f32_16x16x32_bf16(
          af2, bz[vt2], accB[vt2], 0, 0, 0);
  }
  __syncthreads();

  // P write with decay from table
#pragma unroll
  for (int mi = 0; mi < 2; mi++)
#pragma unroll
    for (int nj = 0; nj < 4; nj++)
#pragma unroll
      for (int rg = 0; rg < 4; rg++) {
        int i = ar0 + mi * 16 + q * 4 + rg;
        int j = ac0 + nj * 16 + l16;
        float wv = 0.f;
        if (i > j) wv = pw_s[i - j - 1];
        else if (i == j) wv = u;
        un_s[i * 136 + j] = f2bf(accA[mi][nj][rg] * wv);
      }
  __syncthreads();

  // accO = P @ V via swizzled vt_s ; wave rows 16
  floatx4 accO[4] = {};
#pragma unroll
  for (int js = 0; js < 128; js += 32) {
    bf16x8 af3 = *(const bf16x8*)&un_s[(i0 + l16) * 136 + q * 8 + js];
    int cb = q + (js >> 3);
    bf16x8 bv[4];
#pragma unroll
    for (int vt2 = 0; vt2 < 4; vt2++) {
      int vr = vt2 * 16 + l16;
      bv[vt2] = *(const bf16x8*)&vt_s[vr * 136 + ((cb ^ ((vr >> 3) & 7)) << 3)];
    }
#pragma unroll
    for (int vt2 = 0; vt2 < 4; vt2++)
      accO[vt2] = __builtin_amdgcn_mfma_f32_16x16x32_bf16(
          af3, bv[vt2], accO[vt2], 0, 0, 0);
  }

  // epilogue: +wb*accB, GroupNorm over 64 ch, *g, store
#pragma unroll
  for (int rg = 0; rg < 4; rg++) {
    int i = i0 + q * 4 + rg;
    float wbi = pw_s[i];
    float vals[4];
    float s1 = 0.f, s2 = 0.f;
#pragma unroll
    for (int vt2 = 0; vt2 < 4; vt2++) {
      float val = accO[vt2][rg] + wbi * accB[vt2][rg];
      vals[vt2] = val; s1 += val; s2 += val * val;
    }
#pragma unroll
    for (int mm = 1; mm < 16; mm <<= 1) {
      s1 += __shfl_xor(s1, mm, 64);
      s2 += __shfl_xor(s2, mm, 64);
    }
    float mu = s1 * (1.f / 64.f);
    float va = s2 * (1.f / 64.f) - mu * mu;
    float rinv = rsqrtf(va + 64.f * 1e-5f);
    long rowg = (long)b * TT_DIM + n * T_CH + i;
#pragma unroll
    for (int vt2 = 0; vt2 < 4; vt2++) {
      int c = h * K_DIM + vt2 * 16 + l16;
      float y = (vals[vt2] - mu) * rinv * lnw[c] + lnb[c];
      float gf = bf2f(gBuf[rowg * C_DIM + c]);
      gy[rowg * C_DIM + c] = f2bf(y * gf);
    }
  }
}

// ============================================================
// Buffer flow (stream-ordered, no read/write conflicts):
//   mix:   xq -> b0=xr, b1=xk, b2=xv, b3=xg
//   pair1: {r: b0 -> dL} {k: b1 -> dH}          (d_out as bf16 scratch)
//   pair2: {v: b2 -> b0} {g(silu): b3 -> b1}    (b0,b1 free after pair1)
//   chunk_state(k=dH, v=b0) -> Zc ; state_scan -> Sb
//   chunk_out(r=dL, k=dH, v=b0, g=b1) -> gy=b2
//   o-GEMM: b2 -> d_out fp32 (overwrites dL/dH after last readers)
// ============================================================
extern "C" void kernel_launch(void* const* d_in, const int* in_sizes, int n_in,
                              void* d_out, int out_size, void* d_ws,
                              size_t ws_size, hipStream_t stream) {
  const float* xq  = (const float*)d_in[0];
  const float* tmk = (const float*)d_in[1];
  const float* tmv = (const float*)d_in[2];
  const float* tmr = (const float*)d_in[3];
  const float* tmg = (const float*)d_in[4];
  const float* td  = (const float*)d_in[5];
  const float* tf  = (const float*)d_in[6];
  const float* Wr  = (const float*)d_in[7];
  const float* Wk  = (const float*)d_in[8];
  const float* Wv  = (const float*)d_in[9];
  const float* Wg  = (const float*)d_in[10];
  const float* Wo  = (const float*)d_in[11];
  const float* lnw = (const float*)d_in[12];
  const float* lnb = (const float*)d_in[13];

  char* ws = (char*)d_ws;
  const size_t BUF = (size_t)M_ROWS * C_DIM * 2;  // 32 MiB bf16 buffer
  ushort* b0 = (ushort*)(ws + 0 * BUF);
  ushort* b1 = (ushort*)(ws + 1 * BUF);
  ushort* b2 = (ushort*)(ws + 2 * BUF);
  ushort* b3 = (ushort*)(ws + 3 * BUF);
  ushort* wcv = (ushort*)(ws + 4 * BUF); // 5x 1M bf16 weights (10 MiB)
  const ushort* wr_b = wcv;
  const ushort* wk_b = wcv + (1 << 20);
  const ushort* wv_b = wcv + 2 * (1 << 20);
  const ushort* wg_b = wcv + 3 * (1 << 20);
  const ushort* wo_b = wcv + 4 * (1 << 20);
  ushort* Zc = (ushort*)(ws + 4 * BUF + 5 * (2 << 20));           // 16 MiB
  ushort* Sb = Zc + (size_t)64 * N_CH * 4096;                     // 16 MiB
  ushort* dL = (ushort*)d_out;                       // r (bf16, 32 MiB)
  ushort* dH = dL + (size_t)M_ROWS * C_DIM;          // k (bf16, 32 MiB)

  mix_kernel<<<8192, 256, 0, stream>>>(xq, tmk, tmv, tmr, tmg, b0, b1, b2, b3);
  wconv_kernel<<<2560, 256, 0, stream>>>(Wr, Wk, Wv, Wg, Wo, wcv);

  gemm_pair<0><<<512, 512, 0, stream>>>(b0, wr_b, dL, b1, wk_b, dH);   // r | k
  gemm_pair<1><<<512, 512, 0, stream>>>(b2, wv_b, b0, b3, wg_b, b1);   // v | g

  chunk_state<<<2048, 256, 0, stream>>>(dH, b0, td, Zc);
  state_scan<<<1024, 256, 0, stream>>>(Zc, td, Sb);
  chunk_out<<<2048, 512, 0, stream>>>(dL, dH, b0, b1, Sb, td, tf, lnw, lnb, b2);

  gemm_bt<2><<<256, 512, 0, stream>>>(b2, wo_b, (float*)d_out);  // fp32 out
}

// Round 5
// 405.809 us; speedup vs baseline: 1.0172x; 1.0172x over previous
//
#include <hip/hip_runtime.h>
#include <hip/hip_bf16.h>
#include <stdint.h>

// ---- problem constants ----
#define C_DIM 1024
#define H_DIM 16
#define K_DIM 64
#define T_CH 128
#define TT_DIM 4096
#define B_DIM 4
#define N_CH 32
#define M_ROWS 16384  // B*TT

typedef __attribute__((ext_vector_type(8))) __bf16 bf16x8;
typedef __attribute__((ext_vector_type(4))) float floatx4;

__device__ __forceinline__ float bf2f(ushort u) {
  union { uint32_t i; float f; } v; v.i = ((uint32_t)u) << 16; return v.f;
}
__device__ __forceinline__ ushort f2bf(float f) {
  union { float f; uint32_t i; } v; v.f = f;
  return (ushort)((v.i + 0x7fffu + ((v.i >> 16) & 1u)) >> 16);  // RNE
}

#define GLOAD_LDS16(g, l)                                                     \
  __builtin_amdgcn_global_load_lds(                                           \
      (const __attribute__((address_space(1))) void*)(g),                     \
      (__attribute__((address_space(3))) void*)(l), 16, 0, 0)

// ============================================================
// 1) time-shift mix: xr/xk/xv/xg (bf16) from x (fp32)
//    8 elems/thread, 16B stores.
// ============================================================
__global__ __launch_bounds__(256) void mix_kernel(
    const float* __restrict__ x,
    const float* __restrict__ mk, const float* __restrict__ mv,
    const float* __restrict__ mr, const float* __restrict__ mg,
    ushort* __restrict__ xr, ushort* __restrict__ xk,
    ushort* __restrict__ xv, ushort* __restrict__ xg) {
  long idx = (long)blockIdx.x * 256 + threadIdx.x;
  long e = idx * 8;
  int c = (int)(e & (C_DIM - 1));
  long row = e >> 10;
  int t = (int)(row & (TT_DIM - 1));
  floatx4 xc0 = *(const floatx4*)(x + e);
  floatx4 xc1 = *(const floatx4*)(x + e + 4);
  floatx4 xp0 = {0.f, 0.f, 0.f, 0.f};
  floatx4 xp1 = {0.f, 0.f, 0.f, 0.f};
  if (t != 0) {
    xp0 = *(const floatx4*)(x + e - C_DIM);
    xp1 = *(const floatx4*)(x + e - C_DIM + 4);
  }
  floatx4 d0 = xc0 - xp0;
  floatx4 d1 = xc1 - xp1;
  union { ushort u[8]; uint4 q; } pk;
#define ST(dst, mptr)                                                         \
  {                                                                           \
    floatx4 m0 = *(const floatx4*)((mptr) + c);                               \
    floatx4 m1 = *(const floatx4*)((mptr) + c + 4);                           \
    floatx4 o0 = xp0 + d0 * m0;                                               \
    floatx4 o1 = xp1 + d1 * m1;                                               \
    pk.u[0] = f2bf(o0.x); pk.u[1] = f2bf(o0.y);                               \
    pk.u[2] = f2bf(o0.z); pk.u[3] = f2bf(o0.w);                               \
    pk.u[4] = f2bf(o1.x); pk.u[5] = f2bf(o1.y);                               \
    pk.u[6] = f2bf(o1.z); pk.u[7] = f2bf(o1.w);                               \
    *(uint4*)((dst) + e) = pk.q;                                              \
  }
  ST(xk, mk) ST(xv, mv) ST(xr, mr) ST(xg, mg)
#undef ST
}

// ============================================================
// 2) fp32 -> bf16 weight conversion (5 weights concatenated)
//    8 elems/thread, 16B stores.
// ============================================================
__global__ __launch_bounds__(256) void wconv_kernel(
    const float* __restrict__ w0, const float* __restrict__ w1,
    const float* __restrict__ w2, const float* __restrict__ w3,
    const float* __restrict__ w4, ushort* __restrict__ o) {
  long idx = (long)blockIdx.x * 256 + threadIdx.x;
  long e = idx * 8;
  int wi = (int)(e >> 20);
  long off = e & ((1L << 20) - 1);
  const float* src = wi == 0 ? w0 : wi == 1 ? w1 : wi == 2 ? w2 : wi == 3 ? w3 : w4;
  floatx4 v0 = *(const floatx4*)(src + off);
  floatx4 v1 = *(const floatx4*)(src + off + 4);
  union { ushort u[8]; uint4 q; } pk;
  pk.u[0] = f2bf(v0.x); pk.u[1] = f2bf(v0.y);
  pk.u[2] = f2bf(v0.z); pk.u[3] = f2bf(v0.w);
  pk.u[4] = f2bf(v1.x); pk.u[5] = f2bf(v1.y);
  pk.u[6] = f2bf(v1.z); pk.u[7] = f2bf(v1.w);
  *(uint4*)(o + e) = pk.q;
}

// ============================================================
// 3) bf16 GEMM: C[M,N] = A[M,K] * Bt[N,K]^T  (256x256 8-phase)
//    Round-3 schedule (read-rebalanced, counted vmcnt, setprio).
//    Pairing reverted (round-4 regression): one GEMM per launch.
// ============================================================
#define BARX() __builtin_amdgcn_s_barrier()
#define SCHEDB() __builtin_amdgcn_sched_barrier(0)
#define VMW4() asm volatile("s_waitcnt vmcnt(4)" ::: "memory")
#define VMW0() asm volatile("s_waitcnt vmcnt(0)" ::: "memory")
#define LGKW() asm volatile("s_waitcnt lgkmcnt(0)" ::: "memory")

template <int EPI>
__global__ __launch_bounds__(512, 2) void gemm_bt(
    const ushort* __restrict__ A, const ushort* __restrict__ Bt,
    void* __restrict__ Cout) {
  __shared__ __align__(16) ushort smem[65536];  // 128 KiB
  const int tid = threadIdx.x;
  const int lane = tid & 63, w = tid >> 6;
  const int q = lane >> 4, l16 = lane & 15;
  const int wm = w >> 2, wn = w & 3;
  const int id = blockIdx.x;
  const int wg = (id & 7) * 32 + (id >> 3);
  const int bm = wg >> 2, bn = wg & 3;

  const int r8 = tid >> 3;
  const int c8 = ((tid & 7) ^ (r8 & 7)) * 8;  // pre-swizzled global col
  const ushort* gA = A + (long)(bm * 256 + r8) * C_DIM + c8;
  const ushort* gB = Bt + (long)(bn * 256 + r8) * C_DIM + c8;

  const char* sB = (const char*)smem;
  const int arow = (wm * 128 + l16) * 128;
  const int brow = (wn * 64 + l16) * 128;
  const int swz = (l16 & 7) << 4;
  const int csv[2] = {(q << 4) ^ swz, ((4 + q) << 4) ^ swz};

  floatx4 acc[8][4] = {};
  bf16x8 af[4][2];
  bf16x8 bfv[4][2];

#define STAGE(ISA, sl, hh, tile)                                              \
  do {                                                                        \
    const ushort* g_ = (ISA ? gA : gB) + ((hh) * 131072 + (tile) * 64);       \
    ushort* l_ = smem + ((ISA ? 0 : 32768) + (sl) * 16384 + (hh) * 8192 +     \
                         w * 512);                                            \
    GLOAD_LDS16(g_, l_);                                                      \
    GLOAD_LDS16(g_ + 65536, l_ + 4096);                                       \
  } while (0)

#define READ_A(sl, qr)                                                        \
  do {                                                                        \
    _Pragma("unroll") for (int i_ = 0; i_ < 4; ++i_) {                        \
      af[i_][0] = *(const bf16x8*)(sB + (sl) * 32768 + arow + (qr) * 8192 +   \
                                   i_ * 2048 + csv[0]);                       \
      af[i_][1] = *(const bf16x8*)(sB + (sl) * 32768 + arow + (qr) * 8192 +   \
                                   i_ * 2048 + csv[1]);                       \
    }                                                                         \
  } while (0)

#define READ_B(sl, qc)                                                        \
  do {                                                                        \
    _Pragma("unroll") for (int j_ = 0; j_ < 2; ++j_) {                        \
      bfv[(qc) * 2 + j_][0] = *(const bf16x8*)(sB + 65536 + (sl) * 32768 +    \
                                               brow + (qc) * 4096 +           \
                                               j_ * 2048 + csv[0]);           \
      bfv[(qc) * 2 + j_][1] = *(const bf16x8*)(sB + 65536 + (sl) * 32768 +    \
                                               brow + (qc) * 4096 +           \
                                               j_ * 2048 + csv[1]);           \
    }                                                                         \
  } while (0)

#define MFMA_Q(qr, qc)                                                        \
  do {                                                                        \
    __builtin_amdgcn_s_setprio(1);                                            \
    _Pragma("unroll") for (int i_ = 0; i_ < 4; ++i_)                          \
        _Pragma("unroll") for (int j_ = 0; j_ < 2; ++j_) {                    \
      acc[(qr) * 4 + i_][(qc) * 2 + j_] =                                     \
          __builtin_amdgcn_mfma_f32_16x16x32_bf16(                            \
              af[i_][0], bfv[(qc) * 2 + j_][0],                               \
              acc[(qr) * 4 + i_][(qc) * 2 + j_], 0, 0, 0);                    \
      acc[(qr) * 4 + i_][(qc) * 2 + j_] =                                     \
          __builtin_amdgcn_mfma_f32_16x16x32_bf16(                            \
              af[i_][1], bfv[(qc) * 2 + j_][1],                               \
              acc[(qr) * 4 + i_][(qc) * 2 + j_], 0, 0, 0);                    \
    }                                                                         \
    __builtin_amdgcn_s_setprio(0);                                            \
  } while (0)

  // ---- prologue: A/B of tile0 -> slot0, B of tile1 -> slot1 ----
  STAGE(1, 0, 0, 0); STAGE(1, 0, 1, 0);
  STAGE(0, 0, 0, 0); STAGE(0, 0, 1, 0);
  STAGE(0, 1, 0, 1); STAGE(0, 1, 1, 1);
  VMW4();  // t0's 8 loads done; B-t1's 4 stay in flight
  BARX();
  SCHEDB();
  READ_B(0, 0);  // bfv[0..1] <- B(slot0, qc0)

#pragma unroll 1
  for (int i = 0; i < 7; ++i) {
    const int t1 = 2 * i + 1, tn0 = 2 * i + 2, tn1 = 2 * i + 3;
    READ_A(0, 0); STAGE(1, 1, 0, t1);
    BARX(); SCHEDB(); READ_B(0, 1); MFMA_Q(0, 0); LGKW(); BARX();
    STAGE(1, 1, 1, t1);
    BARX(); SCHEDB(); MFMA_Q(0, 1); LGKW(); BARX();
    READ_A(0, 1); STAGE(0, 0, 0, tn0);
    BARX(); SCHEDB(); MFMA_Q(1, 0); LGKW(); BARX();
    STAGE(0, 0, 1, tn0); VMW4();
    BARX(); SCHEDB(); READ_B(1, 0); MFMA_Q(1, 1); LGKW(); BARX();
    READ_A(1, 0); STAGE(1, 0, 0, tn0);
    BARX(); SCHEDB(); READ_B(1, 1); MFMA_Q(0, 0); LGKW(); BARX();
    STAGE(1, 0, 1, tn0);
    BARX(); SCHEDB(); MFMA_Q(0, 1); LGKW(); BARX();
    READ_A(1, 1); STAGE(0, 1, 0, tn1);
    BARX(); SCHEDB(); MFMA_Q(1, 0); LGKW(); BARX();
    STAGE(0, 1, 1, tn1); VMW4();
    BARX(); SCHEDB(); READ_B(0, 0); MFMA_Q(1, 1); LGKW(); BARX();
  }
  // ---- tail pair (tiles 14,15; only A-15 still needs staging) ----
  READ_A(0, 0); STAGE(1, 1, 0, 15);
  BARX(); SCHEDB(); READ_B(0, 1); MFMA_Q(0, 0); LGKW(); BARX();
  STAGE(1, 1, 1, 15);
  BARX(); SCHEDB(); MFMA_Q(0, 1); LGKW(); BARX();
  READ_A(0, 1);
  BARX(); SCHEDB(); MFMA_Q(1, 0); LGKW(); BARX();
  VMW0();  // drain: tile15 A+B fully landed
  BARX(); SCHEDB(); READ_B(1, 0); MFMA_Q(1, 1); LGKW(); BARX();
  READ_A(1, 0);
  BARX(); SCHEDB(); READ_B(1, 1); MFMA_Q(0, 0); LGKW(); BARX();
  BARX(); SCHEDB(); MFMA_Q(0, 1); LGKW(); BARX();
  READ_A(1, 1);
  BARX(); SCHEDB(); MFMA_Q(1, 0); LGKW(); BARX();
  BARX(); MFMA_Q(1, 1);

  // ---- epilogue: C write ----
  const int row0 = bm * 256 + wm * 128 + q * 4;
  const int col0 = bn * 256 + wn * 64 + l16;
#pragma unroll
  for (int fi = 0; fi < 8; ++fi)
#pragma unroll
    for (int fj = 0; fj < 4; ++fj)
#pragma unroll
      for (int rg = 0; rg < 4; ++rg) {
        long off = (long)(row0 + fi * 16 + rg) * C_DIM + col0 + fj * 16;
        float val = acc[fi][fj][rg];
        if (EPI == 1) val = val / (1.f + expf(-val));  // silu
        if (EPI == 2)
          ((float*)Cout)[off] = val;
        else
          ((ushort*)Cout)[off] = f2bf(val);
      }
#undef STAGE
#undef READ_A
#undef READ_B
#undef MFMA_Q
}

// ============================================================
// 4a) per-chunk state contribution: Zc = vv^T @ (kk*wk)   (bf16)
// ============================================================
__global__ __launch_bounds__(256) void chunk_state(
    const ushort* __restrict__ kB, const ushort* __restrict__ vB,
    const float* __restrict__ td, ushort* __restrict__ Zc) {
  __shared__ __align__(16) ushort vt_s[64 * 136];
  __shared__ __align__(16) ushort kwt_s[64 * 136];
  int blk = blockIdx.x;
  int bh = blk >> 5, n = blk & 31;
  int b = bh >> 4, h = bh & 15;
  int tid = threadIdx.x;
  int lane = tid & 63, w = tid >> 6;
  int q = lane >> 4, l16 = lane & 15;
  float etd = expf(td[h]);
  long cbase = ((long)b * TT_DIM + n * T_CH) * C_DIM + h * K_DIM;

#pragma unroll
  for (int it = 0; it < 4; it++) {
    int chunk = it * 256 + tid;
    int row = chunk >> 3;
    int cc = (chunk & 7) * 8;
    long ga = cbase + (long)row * C_DIM + cc;
    uint4 kv4 = *(const uint4*)(kB + ga);
    uint4 vv4 = *(const uint4*)(vB + ga);
    float wkj = expf(-(float)(T_CH - 1 - row) * etd);
    const ushort* kp = (const ushort*)&kv4;
    const ushort* vp = (const ushort*)&vv4;
    int cb2 = row >> 3;
#pragma unroll
    for (int e2 = 0; e2 < 8; e2++) {
      int vr = cc + e2;
      int ph = vr * 136 + ((cb2 ^ ((vr >> 3) & 7)) << 3) + (row & 7);
      kwt_s[ph] = f2bf(bf2f(kp[e2]) * wkj);
      vt_s[ph] = vp[e2];
    }
  }
  __syncthreads();

  floatx4 accZ[4] = {};
#pragma unroll
  for (int js = 0; js < 128; js += 32) {
    int cb = q + (js >> 3);
    int vrA = w * 16 + l16;
    bf16x8 av = *(const bf16x8*)&vt_s[vrA * 136 + ((cb ^ ((vrA >> 3) & 7)) << 3)];
    bf16x8 bk3[4];
#pragma unroll
    for (int kt = 0; kt < 4; kt++) {
      int vrB = kt * 16 + l16;
      bk3[kt] = *(const bf16x8*)&kwt_s[vrB * 136 + ((cb ^ ((vrB >> 3) & 7)) << 3)];
    }
#pragma unroll
    for (int kt = 0; kt < 4; kt++)
      accZ[kt] = __builtin_amdgcn_mfma_f32_16x16x32_bf16(av, bk3[kt], accZ[kt], 0, 0, 0);
  }
  long zbase = (long)blk * 4096;
#pragma unroll
  for (int kt = 0; kt < 4; kt++)
#pragma unroll
    for (int rg = 0; rg < 4; rg++)
      Zc[zbase + (w * 16 + q * 4 + rg) * 64 + kt * 16 + l16] = f2bf(accZ[kt][rg]);
}

// ============================================================
// 4b) state scan: Sb[bh][n] = state BEFORE chunk n
// ============================================================
__global__ __launch_bounds__(256) void state_scan(
    const ushort* __restrict__ Zc, const float* __restrict__ td,
    ushort* __restrict__ Sb) {
  long tg = (long)blockIdx.x * 256 + threadIdx.x;
  int bh = (int)(tg >> 12);
  int e = (int)(tg & 4095);
  int h = bh & 15;
  float wsf = expf(-128.f * expf(td[h]));
  float s = 0.f;
  long base = (long)bh * N_CH * 4096 + e;
#pragma unroll
  for (int n = 0; n < N_CH; n++) {
    Sb[base + n * 4096] = f2bf(s);
    s = wsf * s + bf2f(Zc[base + n * 4096]);
  }
}

// ============================================================
// 4c) per-chunk output + GroupNorm + *g -> gy (bf16)
// ============================================================
__global__ __launch_bounds__(512, 4) void chunk_out(
    const ushort* __restrict__ rB, const ushort* __restrict__ kB,
    const ushort* __restrict__ vB, const ushort* __restrict__ gBuf,
    const ushort* __restrict__ Sb,
    const float* __restrict__ td, const float* __restrict__ tf,
    const float* __restrict__ lnw, const float* __restrict__ lnb,
    ushort* __restrict__ gy) {
  __shared__ __align__(16) ushort rr_s[128 * 72];
  __shared__ __align__(16) ushort un_s[128 * 136];  // kk then P
  __shared__ __align__(16) ushort vt_s[64 * 136];   // swizzled v^T
  __shared__ __align__(16) ushort z_s[64 * 72];
  __shared__ float pw_s[128];  // decay^d table

  int blk = blockIdx.x;
  int bh = blk >> 5, n = blk & 31;
  int b = bh >> 4, h = bh & 15;
  int tid = threadIdx.x;
  int lane = tid & 63, w = tid >> 6;  // w 0..7
  int q = lane >> 4, l16 = lane & 15;

  float etd = expf(td[h]);
  float u = tf[h];
  long cbase = ((long)b * TT_DIM + n * T_CH) * C_DIM + h * K_DIM;

  if (tid < 128) pw_s[tid] = expf(-(float)tid * etd);

#pragma unroll
  for (int it = 0; it < 2; it++) {
    int chunk = it * 512 + tid;
    int row = chunk >> 3;
    int cc = (chunk & 7) * 8;
    long ga = cbase + (long)row * C_DIM + cc;
    *(uint4*)&rr_s[row * 72 + cc] = *(const uint4*)(rB + ga);
    *(uint4*)&un_s[row * 136 + cc] = *(const uint4*)(kB + ga);
    uint4 vv4 = *(const uint4*)(vB + ga);
    const ushort* vp = (const ushort*)&vv4;
    int cb2 = row >> 3;
#pragma unroll
    for (int e2 = 0; e2 < 8; e2++) {
      int vr = cc + e2;
      vt_s[vr * 136 + ((cb2 ^ ((vr >> 3) & 7)) << 3) + (row & 7)] = vp[e2];
    }
  }
  {
    long sbase = (long)blk * 4096;
    int v = tid >> 3, c0 = (tid & 7) * 8;
    *(uint4*)&z_s[v * 72 + c0] = *(const uint4*)(Sb + sbase + v * 64 + c0);
  }
  __syncthreads();

  // accA: P = r @ kk^T ; wave quadrant 32 rows x 64 cols
  int ar0 = (w >> 1) * 32, ac0 = (w & 1) * 64;
  floatx4 accA[2][4] = {};
#pragma unroll
  for (int ks = 0; ks < 64; ks += 32) {
    bf16x8 af[2], bk2[4];
#pragma unroll
    for (int i = 0; i < 2; i++)
      af[i] = *(const bf16x8*)&rr_s[(ar0 + i * 16 + l16) * 72 + q * 8 + ks];
#pragma unroll
    for (int j = 0; j < 4; j++)
      bk2[j] = *(const bf16x8*)&un_s[(ac0 + j * 16 + l16) * 136 + q * 8 + ks];
#pragma unroll
    for (int mi = 0; mi < 2; mi++)
#pragma unroll
      for (int nj = 0; nj < 4; nj++)
        accA[mi][nj] = __builtin_amdgcn_mfma_f32_16x16x32_bf16(
            af[mi], bk2[nj], accA[mi][nj], 0, 0, 0);
  }

  // accB: r @ S^T ; wave rows 16
  int i0 = w * 16;
  floatx4 accB[4] = {};
#pragma unroll
  for (int ks = 0; ks < 64; ks += 32) {
    bf16x8 af2 = *(const bf16x8*)&rr_s[(i0 + l16) * 72 + q * 8 + ks];
    bf16x8 bz[4];
#pragma unroll
    for (int vt2 = 0; vt2 < 4; vt2++)
      bz[vt2] = *(const bf16x8*)&z_s[(vt2 * 16 + l16) * 72 + q * 8 + ks];
#pragma unroll
    for (int vt2 = 0; vt2 < 4; vt2++)
      accB[vt2] = __builtin_amdgcn_mfma_f32_16x16x32_bf16(
          af2, bz[vt2], accB[vt2], 0, 0, 0);
  }
  __syncthreads();

  // P write with decay from table
#pragma unroll
  for (int mi = 0; mi < 2; mi++)
#pragma unroll
    for (int nj = 0; nj < 4; nj++)
#pragma unroll
      for (int rg = 0; rg < 4; rg++) {
        int i = ar0 + mi * 16 + q * 4 + rg;
        int j = ac0 + nj * 16 + l16;
        float wv = 0.f;
        if (i > j) wv = pw_s[i - j - 1];
        else if (i == j) wv = u;
        un_s[i * 136 + j] = f2bf(accA[mi][nj][rg] * wv);
      }
  __syncthreads();

  // accO = P @ V via swizzled vt_s ; wave rows 16
  floatx4 accO[4] = {};
#pragma unroll
  for (int js = 0; js < 128; js += 32) {
    bf16x8 af3 = *(const bf16x8*)&un_s[(i0 + l16) * 136 + q * 8 + js];
    int cb = q + (js >> 3);
    bf16x8 bv[4];
#pragma unroll
    for (int vt2 = 0; vt2 < 4; vt2++) {
      int vr = vt2 * 16 + l16;
      bv[vt2] = *(const bf16x8*)&vt_s[vr * 136 + ((cb ^ ((vr >> 3) & 7)) << 3)];
    }
#pragma unroll
    for (int vt2 = 0; vt2 < 4; vt2++)
      accO[vt2] = __builtin_amdgcn_mfma_f32_16x16x32_bf16(
          af3, bv[vt2], accO[vt2], 0, 0, 0);
  }

  // epilogue: +wb*accB, GroupNorm over 64 ch, *g, store
#pragma unroll
  for (int rg = 0; rg < 4; rg++) {
    int i = i0 + q * 4 + rg;
    float wbi = pw_s[i];
    float vals[4];
    float s1 = 0.f, s2 = 0.f;
#pragma unroll
    for (int vt2 = 0; vt2 < 4; vt2++) {
      float val = accO[vt2][rg] + wbi * accB[vt2][rg];
      vals[vt2] = val; s1 += val; s2 += val * val;
    }
#pragma unroll
    for (int mm = 1; mm < 16; mm <<= 1) {
      s1 += __shfl_xor(s1, mm, 64);
      s2 += __shfl_xor(s2, mm, 64);
    }
    float mu = s1 * (1.f / 64.f);
    float va = s2 * (1.f / 64.f) - mu * mu;
    float rinv = rsqrtf(va + 64.f * 1e-5f);
    long rowg = (long)b * TT_DIM + n * T_CH + i;
#pragma unroll
    for (int vt2 = 0; vt2 < 4; vt2++) {
      int c = h * K_DIM + vt2 * 16 + l16;
      float y = (vals[vt2] - mu) * rinv * lnw[c] + lnb[c];
      float gf = bf2f(gBuf[rowg * C_DIM + c]);
      gy[rowg * C_DIM + c] = f2bf(y * gf);
    }
  }
}

// ============================================================
extern "C" void kernel_launch(void* const* d_in, const int* in_sizes, int n_in,
                              void* d_out, int out_size, void* d_ws,
                              size_t ws_size, hipStream_t stream) {
  const float* xq  = (const float*)d_in[0];
  const float* tmk = (const float*)d_in[1];
  const float* tmv = (const float*)d_in[2];
  const float* tmr = (const float*)d_in[3];
  const float* tmg = (const float*)d_in[4];
  const float* td  = (const float*)d_in[5];
  const float* tf  = (const float*)d_in[6];
  const float* Wr  = (const float*)d_in[7];
  const float* Wk  = (const float*)d_in[8];
  const float* Wv  = (const float*)d_in[9];
  const float* Wg  = (const float*)d_in[10];
  const float* Wo  = (const float*)d_in[11];
  const float* lnw = (const float*)d_in[12];
  const float* lnb = (const float*)d_in[13];

  char* ws = (char*)d_ws;
  const size_t BUF = (size_t)M_ROWS * C_DIM * 2;  // 32 MiB bf16 buffer
  ushort* b0 = (ushort*)(ws + 0 * BUF);  // xr -> later k
  ushort* b1 = (ushort*)(ws + 1 * BUF);  // xk -> later v
  ushort* b2 = (ushort*)(ws + 2 * BUF);  // xv -> later g(silu)
  ushort* b3 = (ushort*)(ws + 3 * BUF);  // xg -> later gy
  ushort* wcv = (ushort*)(ws + 4 * BUF); // 5x 1M bf16 weights (10 MiB)
  const ushort* wr_b = wcv;
  const ushort* wk_b = wcv + (1 << 20);
  const ushort* wv_b = wcv + 2 * (1 << 20);
  const ushort* wg_b = wcv + 3 * (1 << 20);
  const ushort* wo_b = wcv + 4 * (1 << 20);
  ushort* Zc = (ushort*)(ws + 4 * BUF + 5 * (2 << 20));           // 16 MiB
  ushort* Sb = Zc + (size_t)64 * N_CH * 4096;                     // 16 MiB
  ushort* rbuf = (ushort*)d_out;  // bf16 r parked in d_out scratch (32 MiB)

  mix_kernel<<<8192, 256, 0, stream>>>(xq, tmk, tmv, tmr, tmg, b0, b1, b2, b3);
  wconv_kernel<<<2560, 256, 0, stream>>>(Wr, Wk, Wv, Wg, Wo, wcv);

  gemm_bt<0><<<256, 512, 0, stream>>>(b0, wr_b, rbuf);  // r
  gemm_bt<0><<<256, 512, 0, stream>>>(b1, wk_b, b0);    // k
  gemm_bt<0><<<256, 512, 0, stream>>>(b2, wv_b, b1);    // v
  gemm_bt<1><<<256, 512, 0, stream>>>(b3, wg_b, b2);    // g = silu(xg@Wg^T)

  chunk_state<<<2048, 256, 0, stream>>>(b0, b1, td, Zc);
  state_scan<<<1024, 256, 0, stream>>>(Zc, td, Sb);
  chunk_out<<<2048, 512, 0, stream>>>(rbuf, b0, b1, b2, Sb, td, tf, lnw, lnb, b3);

  gemm_bt<2><<<256, 512, 0, stream>>>(b3, wo_b, (float*)d_out);  // fp32 out
}